// Round 2
// baseline (8415.899 us; speedup 1.0000x reference)
//
#include <hip/hip_runtime.h>
#include <hip/hip_bf16.h>

#define BB 256
#define TT 512
#define DD 256
#define HH 512
#define G4H 2048
#define KTOT 768
#define APITCH 1552   // 768*2 + 16B pad: row stride ≡ 4 banks (mod 32) -> 2-way max on b128 (free)
#define WPITCH 1552

typedef unsigned short u16;
typedef unsigned int u32;
typedef __attribute__((ext_vector_type(8))) short bf16x8;   // 8 bf16 (4 VGPRs)
typedef __attribute__((ext_vector_type(4))) float f32x4;

__device__ __forceinline__ u16 f2bf(float f) {
  union { float f; unsigned u; } v; v.f = f;
  unsigned r = v.u + 0x7FFFu + ((v.u >> 16) & 1u);   // round-to-nearest-even
  return (u16)(r >> 16);
}
__device__ __forceinline__ float bf2f(u16 b) {
  union { unsigned u; float f; } v; v.u = ((unsigned)b) << 16;
  return v.f;
}
__device__ __forceinline__ float fsigmoid(float x) { return 1.f / (1.f + __expf(-x)); }
__device__ __forceinline__ float ftanh(float x) { return 1.f - 2.f / (__expf(2.f * x) + 1.f); }

// Build Wc = [W_hh | W_ih] bf16 [2048][768]; bsum = b_ih + b_hh; zero h0 and flags.
__global__ __launch_bounds__(256) void lstm_init(
    const float* __restrict__ W_ih, const float* __restrict__ W_hh,
    const float* __restrict__ b_ih, const float* __restrict__ b_hh,
    u16* __restrict__ Wc, float* __restrict__ bsum,
    u16* __restrict__ h0, u32* __restrict__ flags)
{
  int idx = blockIdx.x * 256 + threadIdx.x;
  if (idx < G4H * KTOT) {
    int r = idx / KTOT, k = idx - r * KTOT;
    float v = (k < HH) ? W_hh[r * HH + k] : W_ih[r * DD + (k - HH)];
    Wc[idx] = f2bf(v);
  }
  if (idx < G4H) bsum[idx] = b_ih[idx] + b_hh[idx];
  if (idx < BB * HH) h0[idx] = (u16)0;
  if (idx < 256) flags[idx] = 0u;
}

// x f32 -> bf16, 8 elements/thread
__global__ __launch_bounds__(256) void xconv(const float* __restrict__ x, u16* __restrict__ xbf)
{
  size_t i = ((size_t)blockIdx.x * 256 + threadIdx.x) * 8;
  float4 a = *(const float4*)(x + i);
  float4 b = *(const float4*)(x + i + 4);
  bf16x8 v;
  v[0] = (short)f2bf(a.x); v[1] = (short)f2bf(a.y);
  v[2] = (short)f2bf(a.z); v[3] = (short)f2bf(a.w);
  v[4] = (short)f2bf(b.x); v[5] = (short)f2bf(b.y);
  v[6] = (short)f2bf(b.z); v[7] = (short)f2bf(b.w);
  *(bf16x8*)(xbf + i) = v;
}

// Persistent recurrence. Grid 256 WGs (1/CU), WG = (bg of 32 batches) x (sl of 16 hidden).
// W slice resident in LDS all 512 steps; c in registers; h through LLC with
// bg-group-local flag barriers (32 WGs/group; groups are independent).
__global__ __launch_bounds__(256, 1) void lstm_persist(
    const u16* __restrict__ xbf, const u16* __restrict__ Wc,
    const float* __restrict__ bsum, u16* __restrict__ h_buf,
    u32* flags)
{
  __shared__ __align__(16) unsigned char Alds[32 * APITCH];   // 49,664 B
  __shared__ __align__(16) unsigned char Wlds[64 * WPITCH];   // 99,328 B (resident)
  __shared__ float g4[4][32][16];                             //  8,192 B -> 157,184 B total

  const int tid  = threadIdx.x;
  const int bg   = blockIdx.x >> 5;   // batch group (8)
  const int sl   = blockIdx.x & 31;   // hidden slice (32)
  const int lane = tid & 63;
  const int wv   = tid >> 6;
  const int lrow = lane & 15;
  const int lkb  = lane >> 4;

  // ---- one-time: W slice -> LDS (rows r=q*16+u <-> Wc row q*512+sl*16+u)
  #pragma unroll
  for (int j = 0; j < 24; ++j) {
    int c = tid + j * 256;
    int r = c / 96, col = c - r * 96;
    int q = r >> 4, u = r & 15;
    bf16x8 v = *(const bf16x8*)(Wc + (size_t)(q * HH + sl * 16 + u) * KTOT + col * 8);
    *(bf16x8*)(Wlds + r * WPITCH + col * 16) = v;
  }

  // ---- per-thread pointwise constants; cell state lives in registers
  const int pb = tid >> 4;            // batch row 0..15 (and pb+16)
  const int pu = tid & 15;            // hidden unit within slice
  const int hu = sl * 16 + pu;
  const float bi = bsum[hu], bff = bsum[HH + hu], bgg = bsum[2 * HH + hu], bo = bsum[3 * HH + hu];
  float cr0 = 0.f, cr1 = 0.f;
  const int gb0 = bg * 32 + pb, gb1 = gb0 + 16;
  u32* myflags = flags + bg * 32;

  for (int t = 0; t < TT; ++t) {
    const u16* __restrict__ h_in  = h_buf + (t & 1) * (BB * HH);
    u16* __restrict__ h_out = h_buf + ((t + 1) & 1) * (BB * HH);

    // ---- x-part of A (independent of h): 32 rows x 512B, staged before the wait
    #pragma unroll
    for (int j = 0; j < 4; ++j) {
      int c = tid + j * 256;
      int row = c >> 5, col = c & 31;
      bf16x8 v = *(const bf16x8*)(xbf + ((size_t)(bg * 32 + row) * TT + t) * DD + col * 8);
      *(bf16x8*)(Alds + row * APITCH + 1024 + col * 16) = v;
    }
    // ---- wait for step t-1 producers (group-local). Relaxed poll (sc-coherent read
    //      from LLC) + threadfence acquires (buffer_inv L1/L2) before h loads.
    if (t > 0) {
      if (wv == 0 && lane < 32) {
        while (__hip_atomic_load(&myflags[lane], __ATOMIC_RELAXED, __HIP_MEMORY_SCOPE_AGENT) < (u32)t)
          __builtin_amdgcn_s_sleep(1);
      }
      if (wv == 0) __threadfence();
    }
    __syncthreads();

    // ---- phase A: issue h loads to regs; MFMA over x-columns (k 512..767) meanwhile
    bf16x8 hv[8];
    #pragma unroll
    for (int j = 0; j < 8; ++j) {
      int c = tid + j * 256;
      int row = c >> 6, col = c & 63;
      hv[j] = *(const bf16x8*)(h_in + (size_t)(bg * 32 + row) * HH + col * 8);
    }
    f32x4 acc0 = {0.f, 0.f, 0.f, 0.f};
    f32x4 acc1 = {0.f, 0.f, 0.f, 0.f};
    {
      const unsigned aox = (unsigned)(lrow * APITCH + 1024 + lkb * 16);
      const unsigned wox = (unsigned)((wv * 16 + lrow) * WPITCH + 1024 + lkb * 16);
      #pragma unroll
      for (int kc = 0; kc < 8; ++kc) {
        bf16x8 bfr = *(const bf16x8*)(Wlds + wox + kc * 64);
        bf16x8 a0  = *(const bf16x8*)(Alds + aox + kc * 64);
        bf16x8 a1  = *(const bf16x8*)(Alds + aox + 16u * APITCH + kc * 64);
        acc0 = __builtin_amdgcn_mfma_f32_16x16x32_bf16(a0, bfr, acc0, 0, 0, 0);
        acc1 = __builtin_amdgcn_mfma_f32_16x16x32_bf16(a1, bfr, acc1, 0, 0, 0);
      }
    }
    #pragma unroll
    for (int j = 0; j < 8; ++j) {
      int c = tid + j * 256;
      int row = c >> 6, col = c & 63;
      *(bf16x8*)(Alds + row * APITCH + col * 16) = hv[j];
    }
    __syncthreads();

    // ---- phase B: MFMA over h-columns (k 0..511)
    {
      const unsigned ao = (unsigned)(lrow * APITCH + lkb * 16);
      const unsigned wo = (unsigned)((wv * 16 + lrow) * WPITCH + lkb * 16);
      #pragma unroll
      for (int kc = 0; kc < 16; ++kc) {
        bf16x8 bfr = *(const bf16x8*)(Wlds + wo + kc * 64);
        bf16x8 a0  = *(const bf16x8*)(Alds + ao + kc * 64);
        bf16x8 a1  = *(const bf16x8*)(Alds + ao + 16u * APITCH + kc * 64);
        acc0 = __builtin_amdgcn_mfma_f32_16x16x32_bf16(a0, bfr, acc0, 0, 0, 0);
        acc1 = __builtin_amdgcn_mfma_f32_16x16x32_bf16(a1, bfr, acc1, 0, 0, 0);
      }
    }
    // C/D layout (m89): col = lane&15, row = (lane>>4)*4 + reg
    #pragma unroll
    for (int r = 0; r < 4; ++r) {
      g4[wv][lkb * 4 + r][lrow]      = acc0[r];
      g4[wv][16 + lkb * 4 + r][lrow] = acc1[r];
    }
    __syncthreads();

    // ---- pointwise cell update (c in regs), h_out stores
    {
      float gi = g4[0][pb][pu] + bi;
      float gf = g4[1][pb][pu] + bff;
      float gg = g4[2][pb][pu] + bgg;
      float go = g4[3][pb][pu] + bo;
      cr0 = fsigmoid(gf) * cr0 + fsigmoid(gi) * ftanh(gg);
      h_out[(size_t)gb0 * HH + hu] = f2bf(fsigmoid(go) * ftanh(cr0));
      gi = g4[0][pb + 16][pu] + bi;
      gf = g4[1][pb + 16][pu] + bff;
      gg = g4[2][pb + 16][pu] + bgg;
      go = g4[3][pb + 16][pu] + bo;
      cr1 = fsigmoid(gf) * cr1 + fsigmoid(gi) * ftanh(gg);
      h_out[(size_t)gb1 * HH + hu] = f2bf(fsigmoid(go) * ftanh(cr1));
    }
    __syncthreads();   // drains h_out stores to L2 (vmcnt(0) before s_barrier)
    if (tid == 0)      // RELEASE agent store: wbl2 flush then flag visible in LLC
      __hip_atomic_store(&myflags[sl], (u32)(t + 1), __ATOMIC_RELEASE, __HIP_MEMORY_SCOPE_AGENT);
  }
}

// out[b] = sigmoid(h_T[b,:] . fc_w + fc_b); h_T = h_buf[0] (t=511 wrote buffer (511+1)&1 = 0)
__global__ __launch_bounds__(256) void lstm_final(
    const u16* __restrict__ h, const float* __restrict__ fc_w,
    const float* __restrict__ fc_b, float* __restrict__ out)
{
  int b = threadIdx.x;
  float s = 0.f;
  const u16* hp = h + (size_t)b * HH;
  #pragma unroll 8
  for (int k = 0; k < HH; k += 8) {
    bf16x8 v = *(const bf16x8*)(hp + k);
    #pragma unroll
    for (int j = 0; j < 8; ++j) s += bf2f((u16)v[j]) * fc_w[k + j];
  }
  s += fc_b[0];
  out[b] = fsigmoid(s);
}

extern "C" void kernel_launch(void* const* d_in, const int* in_sizes, int n_in,
                              void* d_out, int out_size, void* d_ws, size_t ws_size,
                              hipStream_t stream) {
  (void)in_sizes; (void)n_in; (void)out_size; (void)ws_size;
  const float* x    = (const float*)d_in[0];
  const float* W_ih = (const float*)d_in[1];
  const float* W_hh = (const float*)d_in[2];
  const float* b_ih = (const float*)d_in[3];
  const float* b_hh = (const float*)d_in[4];
  const float* fc_w = (const float*)d_in[5];
  const float* fc_b = (const float*)d_in[6];
  float* out = (float*)d_out;

  char* ws = (char*)d_ws;
  u16*   Wc    = (u16*)(ws);                 // 3,145,728 B
  float* bsum  = (float*)(ws + 3145728);     //     8,192 B
  u16*   h_buf = (u16*)(ws + 3153920);       //   524,288 B (double-buffered h, bf16)
  u32*   flags = (u32*)(ws + 3678208);       //     1,024 B
  u16*   xbf   = (u16*)(ws + 4194304);       // 67,108,864 B (x as bf16) -> ~71 MB total

  lstm_init<<<6144, 256, 0, stream>>>(W_ih, W_hh, b_ih, b_hh, Wc, bsum, h_buf, flags);
  xconv<<<16384, 256, 0, stream>>>(x, xbf);
  void* args[] = { (void*)&xbf, (void*)&Wc, (void*)&bsum, (void*)&h_buf, (void*)&flags };
  (void)hipLaunchCooperativeKernel((void*)lstm_persist, dim3(256), dim3(256), args, 0, stream);
  lstm_final<<<1, 256, 0, stream>>>(h_buf, fc_w, fc_b, out);
}

// Round 3
// 1689.294 us; speedup vs baseline: 4.9819x; 4.9819x over previous
//
#include <hip/hip_runtime.h>
#include <hip/hip_bf16.h>

#define BB 256
#define TT 512
#define DD 256
#define HH 512
#define G4H 2048
#define KTOT 768
#define APITCH 1552   // 768*2 + 16B pad
#define WPITCH 1552

typedef unsigned short u16;
typedef unsigned int u32;
typedef __attribute__((ext_vector_type(8))) short bf16x8;
typedef __attribute__((ext_vector_type(4))) float f32x4;

__device__ __forceinline__ u16 f2bf(float f) {
  union { float f; unsigned u; } v; v.f = f;
  unsigned r = v.u + 0x7FFFu + ((v.u >> 16) & 1u);
  return (u16)(r >> 16);
}
__device__ __forceinline__ float bf2f(u16 b) {
  union { unsigned u; float f; } v; v.u = ((unsigned)b) << 16;
  return v.f;
}
__device__ __forceinline__ float fsigmoid(float x) { return 1.f / (1.f + __expf(-x)); }
__device__ __forceinline__ float ftanh(float x) { return 1.f - 2.f / (__expf(2.f * x) + 1.f); }

// Coherent (LLC-level) accesses: sc0 sc1 flags, no cache maintenance ops.
__device__ __forceinline__ bf16x8 ld16_sc(const u16* p) {
  bf16x8 r;
  asm volatile("global_load_dwordx4 %0, %1, off sc0 sc1" : "=v"(r) : "v"(p) : "memory");
  return r;
}
__device__ __forceinline__ void st4_sc(u16* p, u32 v) {
  asm volatile("global_store_dword %0, %1, off sc0 sc1" :: "v"(p), "v"(v) : "memory");
}
__device__ __forceinline__ void waitv0() {
  asm volatile("s_waitcnt vmcnt(0)" ::: "memory");
}

__global__ __launch_bounds__(256) void lstm_init(
    const float* __restrict__ W_ih, const float* __restrict__ W_hh,
    const float* __restrict__ b_ih, const float* __restrict__ b_hh,
    u16* __restrict__ Wc, float* __restrict__ bsum,
    u16* __restrict__ h0, u32* __restrict__ flags)
{
  int idx = blockIdx.x * 256 + threadIdx.x;
  if (idx < G4H * KTOT) {
    int r = idx / KTOT, k = idx - r * KTOT;
    float v = (k < HH) ? W_hh[r * HH + k] : W_ih[r * DD + (k - HH)];
    Wc[idx] = f2bf(v);
  }
  if (idx < G4H) bsum[idx] = b_ih[idx] + b_hh[idx];
  if (idx < BB * HH) h0[idx] = (u16)0;
  if (idx < 256) flags[idx] = 0u;
}

__global__ __launch_bounds__(256) void xconv(const float* __restrict__ x, u16* __restrict__ xbf)
{
  size_t i = ((size_t)blockIdx.x * 256 + threadIdx.x) * 8;
  float4 a = *(const float4*)(x + i);
  float4 b = *(const float4*)(x + i + 4);
  bf16x8 v;
  v[0] = (short)f2bf(a.x); v[1] = (short)f2bf(a.y);
  v[2] = (short)f2bf(a.z); v[3] = (short)f2bf(a.w);
  v[4] = (short)f2bf(b.x); v[5] = (short)f2bf(b.y);
  v[6] = (short)f2bf(b.z); v[7] = (short)f2bf(b.w);
  *(bf16x8*)(xbf + i) = v;
}

// Persistent recurrence, fence-free sc1 exchange.
// bg = bid&7 (XCD-affine: all 32 WGs of a batch group on one XCD if bid%8 round-robin),
// sl = bid>>3. Correctness does NOT depend on the placement, only speed.
__global__ __launch_bounds__(256, 1) void lstm_persist(
    const u16* __restrict__ xbf, const u16* __restrict__ Wc,
    const float* __restrict__ bsum, u16* __restrict__ h_buf,
    u32* flags)
{
  __shared__ __align__(16) unsigned char Alds[32 * APITCH];   // 49,664 B
  __shared__ __align__(16) unsigned char Wlds[64 * WPITCH];   // 99,328 B (resident)
  __shared__ float g4[4][32][17];                             //  8,704 B -> 157,696 B

  const int tid  = threadIdx.x;
  const int bg   = blockIdx.x & 7;    // batch group (8)  -> XCD-affine
  const int sl   = blockIdx.x >> 3;   // hidden slice (32)
  const int lane = tid & 63;
  const int wv   = tid >> 6;
  const int lrow = lane & 15;
  const int lkb  = lane >> 4;

  // one-time: W slice -> LDS
  #pragma unroll
  for (int j = 0; j < 24; ++j) {
    int c = tid + j * 256;
    int r = c / 96, col = c - r * 96;
    int q = r >> 4, u = r & 15;
    bf16x8 v = *(const bf16x8*)(Wc + (size_t)(q * HH + sl * 16 + u) * KTOT + col * 8);
    *(bf16x8*)(Wlds + r * WPITCH + col * 16) = v;
  }

  // pointwise mapping: batch-major, 2 adjacent units per thread (dword h stores)
  const int pb2 = tid >> 3;              // 0..31 batch within group
  const int pu2 = (tid & 7) * 2;         // 0,2,..,14
  const int hu2 = sl * 16 + pu2;
  const int gb2 = bg * 32 + pb2;
  const float bi0 = bsum[hu2],          bi1 = bsum[hu2 + 1];
  const float bf0 = bsum[HH + hu2],     bf1 = bsum[HH + hu2 + 1];
  const float bg0 = bsum[2 * HH + hu2], bg1 = bsum[2 * HH + hu2 + 1];
  const float bo0 = bsum[3 * HH + hu2], bo1 = bsum[3 * HH + hu2 + 1];
  float c0 = 0.f, c1 = 0.f;
  u32* myflags = flags + bg * 32;

  for (int t = 0; t < TT; ++t) {
    const u16* __restrict__ h_in  = h_buf + (t & 1) * (BB * HH);
    u16* __restrict__ h_out = h_buf + ((t + 1) & 1) * (BB * HH);

    // stage x tile (normal cached loads; overlaps the wait)
    #pragma unroll
    for (int j = 0; j < 4; ++j) {
      int c = tid + j * 256;
      int row = c >> 5, col = c & 31;
      bf16x8 v = *(const bf16x8*)(xbf + ((size_t)(bg * 32 + row) * TT + t) * DD + col * 8);
      *(bf16x8*)(Alds + row * APITCH + 1024 + col * 16) = v;
    }
    // wait for step t-1 producers: relaxed sc1 poll, NO fences
    if (t > 0 && wv == 0 && lane < 32) {
      while (__hip_atomic_load(&myflags[lane], __ATOMIC_RELAXED, __HIP_MEMORY_SCOPE_AGENT) < (u32)t)
        __builtin_amdgcn_s_sleep(1);
    }
    __syncthreads();   // B1

    // issue coherent h loads; x-part MFMA runs while they fly
    bf16x8 hv[8];
    #pragma unroll
    for (int j = 0; j < 8; ++j) {
      int c = tid + j * 256;
      int row = c >> 6, col = c & 63;
      hv[j] = ld16_sc(h_in + (size_t)(bg * 32 + row) * HH + col * 8);
    }
    f32x4 acc0 = {0.f, 0.f, 0.f, 0.f};
    f32x4 acc1 = {0.f, 0.f, 0.f, 0.f};
    {
      const unsigned aox = (unsigned)(lrow * APITCH + 1024 + lkb * 16);
      const unsigned wox = (unsigned)((wv * 16 + lrow) * WPITCH + 1024 + lkb * 16);
      #pragma unroll
      for (int kc = 0; kc < 8; ++kc) {
        bf16x8 bfr = *(const bf16x8*)(Wlds + wox + kc * 64);
        bf16x8 a0  = *(const bf16x8*)(Alds + aox + kc * 64);
        bf16x8 a1  = *(const bf16x8*)(Alds + aox + 16u * APITCH + kc * 64);
        acc0 = __builtin_amdgcn_mfma_f32_16x16x32_bf16(a0, bfr, acc0, 0, 0, 0);
        acc1 = __builtin_amdgcn_mfma_f32_16x16x32_bf16(a1, bfr, acc1, 0, 0, 0);
      }
    }
    waitv0();                                 // h loads complete
    __builtin_amdgcn_sched_barrier(0);        // rule #18: pin against scheduler
    #pragma unroll
    for (int j = 0; j < 8; ++j) {
      int c = tid + j * 256;
      int row = c >> 6, col = c & 63;
      *(bf16x8*)(Alds + row * APITCH + col * 16) = hv[j];
    }
    __syncthreads();   // B2

    // h-part MFMA (k 0..511)
    {
      const unsigned ao = (unsigned)(lrow * APITCH + lkb * 16);
      const unsigned wo = (unsigned)((wv * 16 + lrow) * WPITCH + lkb * 16);
      #pragma unroll
      for (int kc = 0; kc < 16; ++kc) {
        bf16x8 bfr = *(const bf16x8*)(Wlds + wo + kc * 64);
        bf16x8 a0  = *(const bf16x8*)(Alds + ao + kc * 64);
        bf16x8 a1  = *(const bf16x8*)(Alds + ao + 16u * APITCH + kc * 64);
        acc0 = __builtin_amdgcn_mfma_f32_16x16x32_bf16(a0, bfr, acc0, 0, 0, 0);
        acc1 = __builtin_amdgcn_mfma_f32_16x16x32_bf16(a1, bfr, acc1, 0, 0, 0);
      }
    }
    #pragma unroll
    for (int r = 0; r < 4; ++r) {
      g4[wv][lkb * 4 + r][lrow]      = acc0[r];
      g4[wv][16 + lkb * 4 + r][lrow] = acc1[r];
    }
    __syncthreads();   // B3

    // pointwise cell update; packed dword h store (coherent)
    {
      float gi0 = g4[0][pb2][pu2]     + bi0, gi1 = g4[0][pb2][pu2 + 1] + bi1;
      float gf_0 = g4[1][pb2][pu2]    + bf0, gf_1 = g4[1][pb2][pu2 + 1] + bf1;
      float gg0 = g4[2][pb2][pu2]     + bg0, gg1 = g4[2][pb2][pu2 + 1] + bg1;
      float go0 = g4[3][pb2][pu2]     + bo0, go1 = g4[3][pb2][pu2 + 1] + bo1;
      c0 = fsigmoid(gf_0) * c0 + fsigmoid(gi0) * ftanh(gg0);
      c1 = fsigmoid(gf_1) * c1 + fsigmoid(gi1) * ftanh(gg1);
      u32 ha = (u32)f2bf(fsigmoid(go0) * ftanh(c0));
      u32 hb = (u32)f2bf(fsigmoid(go1) * ftanh(c1));
      st4_sc(h_out + (size_t)gb2 * HH + hu2, ha | (hb << 16));
    }
    waitv0();          // own h stores at coherent point
    __syncthreads();   // B4: all threads' stores done
    if (tid == 0)      // relaxed flag store (sc1, NO wbl2)
      __hip_atomic_store(&myflags[sl], (u32)(t + 1), __ATOMIC_RELAXED, __HIP_MEMORY_SCOPE_AGENT);
  }
}

__global__ __launch_bounds__(256) void lstm_final(
    const u16* __restrict__ h, const float* __restrict__ fc_w,
    const float* __restrict__ fc_b, float* __restrict__ out)
{
  int b = threadIdx.x;
  float s = 0.f;
  const u16* hp = h + (size_t)b * HH;
  #pragma unroll 8
  for (int k = 0; k < HH; k += 8) {
    bf16x8 v = *(const bf16x8*)(hp + k);
    #pragma unroll
    for (int j = 0; j < 8; ++j) s += bf2f((u16)v[j]) * fc_w[k + j];
  }
  s += fc_b[0];
  out[b] = fsigmoid(s);
}

extern "C" void kernel_launch(void* const* d_in, const int* in_sizes, int n_in,
                              void* d_out, int out_size, void* d_ws, size_t ws_size,
                              hipStream_t stream) {
  (void)in_sizes; (void)n_in; (void)out_size; (void)ws_size;
  const float* x    = (const float*)d_in[0];
  const float* W_ih = (const float*)d_in[1];
  const float* W_hh = (const float*)d_in[2];
  const float* b_ih = (const float*)d_in[3];
  const float* b_hh = (const float*)d_in[4];
  const float* fc_w = (const float*)d_in[5];
  const float* fc_b = (const float*)d_in[6];
  float* out = (float*)d_out;

  char* ws = (char*)d_ws;
  u16*   Wc    = (u16*)(ws);                 // 3,145,728 B
  float* bsum  = (float*)(ws + 3145728);     //     8,192 B
  u16*   h_buf = (u16*)(ws + 3153920);       //   524,288 B
  u32*   flags = (u32*)(ws + 3678208);       //     1,024 B
  u16*   xbf   = (u16*)(ws + 4194304);       // 67,108,864 B

  lstm_init<<<6144, 256, 0, stream>>>(W_ih, W_hh, b_ih, b_hh, Wc, bsum, h_buf, flags);
  xconv<<<16384, 256, 0, stream>>>(x, xbf);
  void* args[] = { (void*)&xbf, (void*)&Wc, (void*)&bsum, (void*)&h_buf, (void*)&flags };
  (void)hipLaunchCooperativeKernel((void*)lstm_persist, dim3(256), dim3(256), args, 0, stream);
  lstm_final<<<1, 256, 0, stream>>>(h_buf, fc_w, fc_b, out);
}